// Round 1
// baseline (150.348 us; speedup 1.0000x reference)
//
#include <hip/hip_runtime.h>

// HyperbolicMultiheadAttention — algebraically simplified.
//
// The reference computes w = exp(-arccosh(max(cos_sim, 1))) which is
// identically 1 (cosine sim of unit vectors <= 1), so attention output is
// a q-independent sum over V rows. Head split/merge is a pure reshape, and
// the V projection commutes with the sequence sum:
//   d_out[b,s,:] = ((sum_s value[b,s,:]) @ w_v^T + S*b_v) @ w_o^T + b_o
// Q/K projections and the S x S score matrix are dead code.

constexpr int B = 4;
constexpr int S = 2048;
constexpr int D = 1024;
constexpr int SCHUNK = 32;
constexpr int NCHUNK = S / SCHUNK;  // 64

// partial[b,c,d] = sum over the c-th chunk of 32 rows of value[b,s,d]
__global__ void k_colsum_partial(const float* __restrict__ value,
                                 float* __restrict__ partial) {
  const int d = blockIdx.x * blockDim.x + threadIdx.x;  // gridDim.x = D/256
  const int c = blockIdx.y;                              // 0..NCHUNK-1
  const int b = blockIdx.z;                              // 0..B-1
  const float* p = value + (((size_t)b * S) + (size_t)c * SCHUNK) * D + d;
  float acc = 0.f;
#pragma unroll
  for (int i = 0; i < SCHUNK; ++i) acc += p[(size_t)i * D];
  partial[(((size_t)b * NCHUNK) + c) * D + d] = acc;
}

// vsum[b,d] = sum_c partial[b,c,d]
__global__ void k_colsum_reduce(const float* __restrict__ partial,
                                float* __restrict__ vsum) {
  const int d = blockIdx.x * blockDim.x + threadIdx.x;
  const int b = blockIdx.y;
  const float* p = partial + (size_t)b * NCHUNK * D + d;
  float acc = 0.f;
#pragma unroll
  for (int c = 0; c < NCHUNK; ++c) acc += p[(size_t)c * D];
  vsum[(size_t)b * D + d] = acc;
}

// y[b,j] = dot(x[b,:], w[j,:]) + bias_scale * bias[j]
// grid = D blocks (one per j), block = 256 = 4 waves (one per batch b).
__global__ void k_gemv4(const float* __restrict__ x, const float* __restrict__ w,
                        const float* __restrict__ bias, float bias_scale,
                        float* __restrict__ y) {
  const int j = blockIdx.x;
  const int lane = threadIdx.x & 63;
  const int b = threadIdx.x >> 6;
  const float4* wr = (const float4*)(w + (size_t)j * D);
  const float4* xr = (const float4*)(x + (size_t)b * D);
  float acc = 0.f;
#pragma unroll
  for (int i = 0; i < D / 4 / 64; ++i) {  // 4 iters
    float4 a = wr[lane + 64 * i];
    float4 c = xr[lane + 64 * i];
    acc += a.x * c.x + a.y * c.y + a.z * c.z + a.w * c.w;
  }
#pragma unroll
  for (int off = 32; off; off >>= 1) acc += __shfl_xor(acc, off, 64);
  if (lane == 0) y[(size_t)b * D + j] = acc + bias_scale * bias[j];
}

// d_out[b,s,:] = fin[b,:] broadcast over s; float4-vectorized writes.
__global__ void k_bcast(const float* __restrict__ fin, float4* __restrict__ out) {
  const size_t idx = (size_t)blockIdx.x * blockDim.x + threadIdx.x;  // B*S*D/4 units
  const int dp = (int)(idx & (D / 4 - 1));
  const size_t row = idx >> 8;     // idx / (D/4)
  const int b = (int)(row >> 11);  // row / S
  out[idx] = ((const float4*)fin)[b * (D / 4) + dp];
}

extern "C" void kernel_launch(void* const* d_in, const int* in_sizes, int n_in,
                              void* d_out, int out_size, void* d_ws, size_t ws_size,
                              hipStream_t stream) {
  // setup_inputs order: query,key,value,w_q,b_q,w_k,b_k,w_v,b_v,w_o,b_o
  const float* value = (const float*)d_in[2];
  const float* w_v = (const float*)d_in[7];
  const float* b_v = (const float*)d_in[8];
  const float* w_o = (const float*)d_in[9];
  const float* b_o = (const float*)d_in[10];

  float* ws = (float*)d_ws;
  float* partial = ws;                                 // B*NCHUNK*D = 256K floats
  float* vsum = partial + (size_t)B * NCHUNK * D;      // B*D
  float* attn = vsum + (size_t)B * D;                  // B*D
  float* fin = attn + (size_t)B * D;                   // B*D

  dim3 g1(D / 256, NCHUNK, B);
  k_colsum_partial<<<g1, 256, 0, stream>>>(value, partial);

  dim3 g2(D / 256, B);
  k_colsum_reduce<<<g2, 256, 0, stream>>>(partial, vsum);

  k_gemv4<<<D, 256, 0, stream>>>(vsum, w_v, b_v, (float)S, attn);
  k_gemv4<<<D, 256, 0, stream>>>(attn, w_o, b_o, 1.0f, fin);

  const size_t n4 = (size_t)B * S * D / 4;  // 2,097,152
  k_bcast<<<(unsigned)(n4 / 256), 256, 0, stream>>>(fin, (float4*)d_out);
}